// Round 15
// baseline (112.219 us; speedup 1.0000x reference)
//
#include <hip/hip_runtime.h>

// Requires ws_size >= 48 MiB.
typedef short bf16x8 __attribute__((ext_vector_type(8)));
typedef float f32x4 __attribute__((ext_vector_type(4)));
typedef float f32x16 __attribute__((ext_vector_type(16)));
typedef unsigned short ushort8 __attribute__((ext_vector_type(8)));
typedef unsigned short ushort4v __attribute__((ext_vector_type(4)));
typedef unsigned int uint4v __attribute__((ext_vector_type(4)));
typedef unsigned short u16;

__device__ inline u16 f2bf(float f) {
  unsigned int u = __float_as_uint(f);
  u += 0x7fffu + ((u >> 16) & 1u);
  return (u16)(u >> 16);
}

__device__ inline unsigned cvt_pk_bf16(float lo, float hi2) {
  unsigned r;
  asm("v_cvt_pk_bf16_f32 %0, %1, %2" : "=v"(r) : "v"(lo), "v"(hi2));
  return r;
}

// NOTE: only safe with two DISTINCT live inputs (R5 bug: a==b coalesces).
__device__ inline void perm32swap(unsigned& a, unsigned& b) {
  asm("v_permlane32_swap_b32 %0, %1" : "+v"(a), "+v"(b));
}

__device__ inline void gload_lds16(const u16* g, u16* l) {
  __builtin_amdgcn_global_load_lds(
      (const __attribute__((address_space(1))) unsigned int*)g,
      (__attribute__((address_space(3))) unsigned int*)l, 16, 0, 0);
}

// Counted vmcnt wait + scheduling fence (rule #18).
#define WAITVM(NSTR)                           \
  do {                                         \
    asm volatile("s_waitcnt vmcnt(" NSTR ")"); \
    __builtin_amdgcn_sched_barrier(0);         \
  } while (0)

// ---------------- elementwise f32 -> bf16 ----------------
__global__ __launch_bounds__(256) void cvt_bf16(const float* __restrict__ in,
                                                u16* __restrict__ out, int n) {
  int i = (blockIdx.x * 256 + threadIdx.x) * 8;
  if (i >= n) return;
  float4 a = *(const float4*)(in + i);
  float4 b = *(const float4*)(in + i + 4);
  ushort8 o;
  o[0] = f2bf(a.x); o[1] = f2bf(a.y); o[2] = f2bf(a.z); o[3] = f2bf(a.w);
  o[4] = f2bf(b.x); o[5] = f2bf(b.y); o[6] = f2bf(b.z); o[7] = f2bf(b.w);
  *(ushort8*)(out + i) = o;
}

// ---------------- W[K][N] f32 -> Wt[N][K] bf16 ----------------
__global__ __launch_bounds__(256) void trans_w(const float* __restrict__ W,
                                               u16* __restrict__ Wt, int K, int N) {
  const int k0 = blockIdx.x * 64, n0 = blockIdx.y * 64;
  const int tx = threadIdx.x & 63, ty = threadIdx.x >> 6;
  __shared__ float t[64][65];
#pragma unroll
  for (int i = 0; i < 16; ++i) {
    int r = i * 4 + ty;
    t[r][tx] = W[(size_t)(k0 + r) * N + n0 + tx];
  }
  __syncthreads();
#pragma unroll
  for (int i = 0; i < 16; ++i) {
    int r = i * 4 + ty;
    Wt[(size_t)(n0 + r) * K + k0 + tx] = f2bf(t[tx][r]);
  }
}

// ------ QKV GEMM v2: 256x256 tile, BK=32, 4-slot counted-vmcnt pipeline ----
// Per K-tile: vmcnt(8) -> ONE barrier -> stage(t+3) -> 12 ds_read + 32 MFMA.
// The vmem queue never drains in the main loop (T4); loads have 3 compute
// phases to land. Slot rotation is race-free: slot (t+3)&3's last reader is
// tile t-1, and all waves pass barrier(t) before stage(t+3) issues.
// Both-sides XOR swizzle: LDS (row,slot16B) holds A[row][(slot^(row&3))*8..].
// Epilogue: fragment-packed Q/K/V scatter (verified in R14).
__global__ __launch_bounds__(512, 1) void gemm256_qkv(
    const u16* __restrict__ A, const u16* __restrict__ Bt,
    const float* __restrict__ bias, u16* __restrict__ Qb,
    u16* __restrict__ Kb, u16* __restrict__ Vb) {
  const int K = 1024;
  const int lid = blockIdx.x;
  const int swz = (lid & 7) * 24 + (lid >> 3);   // XCD-chunked bijective
  const int bm = (swz & 15) * 256;
  const int bn = (swz >> 4) * 256;

  const int tid = threadIdx.x;
  const int wid = tid >> 6;        // 0..7
  const int lane = tid & 63;
  const int lr = lane & 15;
  const int lg = (lane >> 4) & 3;
  const int wr = wid >> 2;         // 0..1  (M)
  const int wc = wid & 3;          // 0..3  (N)

  __shared__ u16 smem[65536];      // 128 KiB: A slots [4][8192], B slots [4][8192]

  f32x4 acc[8][4] = {};

  const u16* Ag = A + (size_t)bm * K;
  const u16* Bg = Bt + (size_t)bn * K;

  // staging: thread tid covers (row = tid/4, slot16B = tid%4) of rows 0..127
  // and row+128; value at (row, sl) is M[row][kt*32 + (sl^(row&3))*8 ..+8]
  const int srow = tid >> 2;           // 0..127
  const int ssl = tid & 3;
  const int scol = (ssl ^ (srow & 3)) * 8;

  auto stage = [&](int t) {
    const int kof = t * 32;
    u16* As = smem + (t & 3) * 8192;
    u16* Bs = smem + 32768 + (t & 3) * 8192;
    gload_lds16(Ag + (size_t)srow * K + kof + scol, As + tid * 8);
    gload_lds16(Ag + (size_t)(srow + 128) * K + kof + scol, As + 4096 + tid * 8);
    gload_lds16(Bg + (size_t)srow * K + kof + scol, Bs + tid * 8);
    gload_lds16(Bg + (size_t)(srow + 128) * K + kof + scol, Bs + 4096 + tid * 8);
  };

  auto compute = [&](int slot) {
    const char* Ard = (const char*)(smem + slot * 8192);
    const char* Brd = (const char*)(smem + 32768 + slot * 8192);
    const int rsw = (lg ^ (lr & 3)) * 16;   // swizzled 16B slot within 64B row
    bf16x8 af[8], bfr[4];
#pragma unroll
    for (int t = 0; t < 8; ++t) {
      const int ra = wr * 128 + t * 16 + lr;
      af[t] = *(const bf16x8*)(Ard + ra * 64 + rsw);
    }
#pragma unroll
    for (int t = 0; t < 4; ++t) {
      const int rb = wc * 64 + t * 16 + lr;
      bfr[t] = *(const bf16x8*)(Brd + rb * 64 + rsw);
    }
    __builtin_amdgcn_s_setprio(1);
#pragma unroll
    for (int mt = 0; mt < 8; ++mt)
#pragma unroll
      for (int nt = 0; nt < 4; ++nt)
        acc[mt][nt] = __builtin_amdgcn_mfma_f32_16x16x32_bf16(
            af[mt], bfr[nt], acc[mt][nt], 0, 0, 0);
    __builtin_amdgcn_s_setprio(0);
  };

  // prologue: 3 tiles in flight (12 loads/thread outstanding)
  stage(0);
  stage(1);
  stage(2);

  for (int t = 0; t < 32; ++t) {
    if (t <= 29)
      WAITVM("8");        // confirms tile t landed; t+1,t+2 stay in flight
    else if (t == 30)
      WAITVM("4");
    else
      WAITVM("0");
    __builtin_amdgcn_s_barrier();   // publishes tile t; slot (t+3)&3 now free
    if (t + 3 < 32) stage(t + 3);
    compute(t & 3);
  }

  // ---- epilogue: acc -> swizzled LDS bounce tile T (512-B rows) -> ----
  // ---- coalesced fragment-packed global stores (verified R14).     ----
  __syncthreads();
  u16* T = smem;
  const int which = bn >> 10;  // 0=Q, 1=K, 2=V

  if (which == 2) {
#pragma unroll
    for (int nt = 0; nt < 4; ++nt) {
      const int cl = wc * 64 + nt * 16 + lr;
      const float bv = bias[bn + cl];
#pragma unroll
      for (int mt = 0; mt < 8; ++mt) {
        const int rlb = wr * 256 + mt * 32 + lg * 8;
        ushort4v pk;
#pragma unroll
        for (int r = 0; r < 4; ++r) pk[r] = f2bf(acc[mt][nt][r] + bv);
        *(ushort4v*)((char*)T + cl * 512 + (rlb ^ ((cl & 7) << 4))) = pk;
      }
    }
  } else {
    const float sc = (which == 0) ? 0.18033688f : 1.0f;
#pragma unroll
    for (int mt = 0; mt < 8; ++mt) {
      const int rl0 = wr * 128 + mt * 16 + lg * 4;
#pragma unroll
      for (int nt = 0; nt < 4; ++nt) {
        const int cl = wc * 64 + nt * 16 + lr;
        const float bv = bias[bn + cl];
#pragma unroll
        for (int r = 0; r < 4; ++r) {
          const int rl = rl0 + r;
          *(u16*)((char*)T + rl * 512 + ((cl * 2) ^ ((rl & 7) << 4))) =
              f2bf((acc[mt][nt][r] + bv) * sc);
        }
      }
    }
  }
  __syncthreads();

  const int b = bm >> 11;
  const int nbase = bm & 2047;
  if (which == 0) {
#pragma unroll
    for (int i = 0; i < 16; ++i) {
      const int c = i * 512 + tid;
      const int rl = c >> 5, dch = c & 31;
      uint4v v =
          *(const uint4v*)((const char*)T + rl * 512 + ((dch * 16) ^ ((rl & 7) << 4)));
      const int bh = b * 16 + (bn >> 6) + (dch >> 3);
      *(uint4v*)(Qb + ((size_t)bh * 2048 + nbase + rl) * 64 + (dch & 7) * 8) = v;
    }
  } else if (which == 1) {
#pragma unroll
    for (int i = 0; i < 16; ++i) {
      const int c = i * 512 + tid;
      const int ln = c & 63, s = (c >> 6) & 7, ktl = (c >> 9) & 3, hl = (c >> 11) & 3;
      const int lq = ln & 31, hi2 = ln >> 5;
      const int rl = ktl * 64 + (s & 1) * 32 + lq;
      const int cc = hl * 128 + (s >> 1) * 32 + hi2 * 16;
      uint4v v = *(const uint4v*)((const char*)T + rl * 512 + (cc ^ ((rl & 7) << 4)));
      const int bh = b * 16 + ((bn & 1023) >> 6) + hl;
      const int kt2 = (nbase >> 6) + ktl;
      *(uint4v*)(Kb + ((((size_t)bh * 32 + kt2) * 8 + s) * 64 + ln) * 8) = v;
    }
  } else {
#pragma unroll
    for (int i = 0; i < 16; ++i) {
      const int c = i * 512 + tid;
      const int ln = c & 63, s = (c >> 6) & 7, ktl = (c >> 9) & 3, hl = (c >> 11) & 3;
      const int lq = ln & 31, hi2 = ln >> 5;
      const int cl = hl * 64 + (s & 1) * 32 + lq;
      const int cc = ktl * 128 + (s >> 1) * 32 + hi2 * 16;
      uint4v v = *(const uint4v*)((const char*)T + cl * 512 + (cc ^ ((cl & 7) << 4)));
      const int bh = b * 16 + ((bn & 1023) >> 6) + hl;
      const int kt2 = (nbase >> 6) + ktl;
      *(uint4v*)(Vb + ((((size_t)bh * 32 + kt2) * 8 + s) * 64 + ln) * 8) = v;
    }
  }
}

// ---------------- proj GEMM: 128^2 tile, 2-phase (unchanged) ----------------
__global__ __launch_bounds__(256) void gemm_proj(
    const u16* __restrict__ A, const u16* __restrict__ Bt, int M, int N, int K,
    const float* __restrict__ bias, float* __restrict__ outF) {
  const int bm = blockIdx.x * 128;
  const int bn = blockIdx.y * 128;
  const int tid = threadIdx.x;
  const int wid = tid >> 6;
  const int lr = tid & 15;
  const int lg = (tid >> 4) & 3;
  const int wr = wid >> 1, wc = wid & 1;

  __shared__ u16 smem[32768];
  u16* Ab0 = smem;
  u16* Ab1 = smem + 8192;
  u16* Bb0 = smem + 16384;
  u16* Bb1 = smem + 24576;

  f32x4 acc[4][4] = {};

  const int rowi = tid >> 3;
  const int sslot = ((tid & 7) ^ (rowi & 7)) * 8;
  const u16* Ag = A + (size_t)bm * K;
  const u16* Bg = Bt + (size_t)bn * K;
  const int nkt = K >> 6;

  auto stage = [&](u16* Ad, u16* Bd, int kt) {
    const int kof = kt << 6;
#pragma unroll
    for (int i = 0; i < 4; ++i) {
      const int row = i * 32 + rowi;
      gload_lds16(Ag + (size_t)row * K + kof + sslot, Ad + (i * 32 + wid * 8) * 64);
      gload_lds16(Bg + (size_t)row * K + kof + sslot, Bd + (i * 32 + wid * 8) * 64);
    }
  };

  stage(Ab0, Bb0, 0);
  __syncthreads();

  for (int kt = 0; kt < nkt; ++kt) {
    const int p = kt & 1;
    const char* Ard = (const char*)(p ? Ab1 : Ab0);
    const char* Brd = (const char*)(p ? Bb1 : Bb0);
    bf16x8 af[4], bfr[4];
#pragma unroll
    for (int t = 0; t < 4; ++t) {
      const int ra = wr * 64 + t * 16 + lr;
      const int rb = wc * 64 + t * 16 + lr;
      af[t] = *(const bf16x8*)(Ard + ra * 128 + ((lg * 16) ^ ((ra & 7) << 4)));
      bfr[t] = *(const bf16x8*)(Brd + rb * 128 + ((lg * 16) ^ ((rb & 7) << 4)));
    }
    if (kt + 1 < nkt) stage(p ? Ab0 : Ab1, p ? Bb0 : Bb1, kt + 1);
    __builtin_amdgcn_s_setprio(1);
#pragma unroll
    for (int mt = 0; mt < 4; ++mt)
#pragma unroll
      for (int nt = 0; nt < 4; ++nt)
        acc[mt][nt] = __builtin_amdgcn_mfma_f32_16x16x32_bf16(
            af[mt], bfr[nt], acc[mt][nt], 0, 0, 0);
    __builtin_amdgcn_s_setprio(0);
#pragma unroll
    for (int t = 0; t < 4; ++t) {
      const int ra = wr * 64 + t * 16 + lr;
      const int rb = wc * 64 + t * 16 + lr;
      af[t] = *(const bf16x8*)(Ard + ra * 128 + ((64 + lg * 16) ^ ((ra & 7) << 4)));
      bfr[t] = *(const bf16x8*)(Brd + rb * 128 + ((64 + lg * 16) ^ ((rb & 7) << 4)));
    }
    __builtin_amdgcn_s_setprio(1);
#pragma unroll
    for (int mt = 0; mt < 4; ++mt)
#pragma unroll
      for (int nt = 0; nt < 4; ++nt)
        acc[mt][nt] = __builtin_amdgcn_mfma_f32_16x16x32_bf16(
            af[mt], bfr[nt], acc[mt][nt], 0, 0, 0);
    __builtin_amdgcn_s_setprio(0);
    __syncthreads();
  }

#pragma unroll
  for (int mt = 0; mt < 4; ++mt) {
    const int row0 = bm + wr * 64 + mt * 16 + lg * 4;
#pragma unroll
    for (int nt = 0; nt < 4; ++nt) {
      const int col = bn + wc * 64 + nt * 16 + lr;
      const float bv = bias[col];
#pragma unroll
      for (int r = 0; r < 4; ++r)
        outF[(size_t)(row0 + r) * N + col] = acc[mt][nt][r] + bv;
    }
  }
}

// ------- flash attention v12: KVBLK=128, two staggered chains per phase -----
// (unchanged; ~52 us profiled, VGPR 104, no spill)
__global__ __launch_bounds__(256, 2) void flash_attn12(const u16* __restrict__ Qb,
                                                       const u16* __restrict__ Kp,
                                                       const u16* __restrict__ Vp,
                                                       u16* __restrict__ AO) {
  const int bh = blockIdx.x & 31;
  const int qt = blockIdx.x >> 5;   // 0..15
  const int tid = threadIdx.x;
  const int w = tid >> 6;
  const int lane = tid & 63;
  const int lq = lane & 31;
  const int hi = lane >> 5;
  const int q0 = qt * 128 + w * 32;

  __shared__ u16 Kld[2][8192];
  __shared__ u16 Vld[2][8192];

  const u16* Qg = Qb + ((size_t)bh * 2048 + q0 + lq) * 64 + 8 * hi;
  bf16x8 qf[4];
#pragma unroll
  for (int t = 0; t < 4; ++t) qf[t] = *(const bf16x8*)(Qg + 16 * t);

  const u16* Kg = Kp + (size_t)bh * (32 * 4096);
  const u16* Vg = Vp + (size_t)bh * (32 * 4096);

  f32x16 ot0 = {}, ot1 = {};
  float lacc[8] = {};

  auto stage = [&](int p, int ph) {
    const size_t src = (size_t)ph * 8192;
#pragma unroll
    for (int j = 0; j < 4; ++j) {
      gload_lds16(Kg + src + j * 2048 + tid * 8, &Kld[p][j * 2048 + tid * 8]);
      gload_lds16(Vg + src + j * 2048 + tid * 8, &Vld[p][j * 2048 + tid * 8]);
    }
  };

  auto compute = [&](int p) {
    bf16x8 kf0[8], kf1[8];
#pragma unroll
    for (int s = 0; s < 8; ++s) {
      kf0[s] = *(const bf16x8*)&Kld[p][s * 512 + lane * 8];
      kf1[s] = *(const bf16x8*)&Kld[p][4096 + s * 512 + lane * 8];
    }

    f32x16 sa0 = {}, sb0 = {}, sa1 = {}, sb1 = {};
    __builtin_amdgcn_s_setprio(1);
#pragma unroll
    for (int t = 0; t < 4; ++t) {
      sa0 = __builtin_amdgcn_mfma_f32_32x32x16_bf16(kf0[2 * t], qf[t], sa0, 0, 0, 0);
      sb0 = __builtin_amdgcn_mfma_f32_32x32x16_bf16(kf0[2 * t + 1], qf[t], sb0, 0, 0, 0);
      sa1 = __builtin_amdgcn_mfma_f32_32x32x16_bf16(kf1[2 * t], qf[t], sa1, 0, 0, 0);
      sb1 = __builtin_amdgcn_mfma_f32_32x32x16_bf16(kf1[2 * t + 1], qf[t], sb1, 0, 0, 0);
    }
    __builtin_amdgcn_s_setprio(0);

    bf16x8 vf0[8];
#pragma unroll
    for (int s = 0; s < 8; ++s)
      vf0[s] = *(const bf16x8*)&Vld[p][s * 512 + lane * 8];

#pragma unroll
    for (int r = 0; r < 16; ++r) {
      sa0[r] = __builtin_amdgcn_exp2f(sa0[r]);
      sb0[r] = __builtin_amdgcn_exp2f(sb0[r]);
    }
#pragma unroll
    for (int r = 0; r < 8; ++r)
      lacc[r] += (sa0[r] + sa0[r + 8]) + (sb0[r] + sb0[r + 8]);

    unsigned Ua[8], Ub[8];
#pragma unroll
    for (int s = 0; s < 4; ++s)
#pragma unroll
      for (int m2 = 0; m2 < 2; ++m2) {
        Ua[s * 2 + m2] = cvt_pk_bf16(sa0[4 * s + 2 * m2], sa0[4 * s + 2 * m2 + 1]);
        Ub[s * 2 + m2] = cvt_pk_bf16(sb0[4 * s + 2 * m2], sb0[4 * s + 2 * m2 + 1]);
      }
    bf16x8 pfrag[4];
#pragma unroll
    for (int t = 0; t < 4; ++t) {
      const unsigned* U = (t < 2) ? Ua : Ub;
      const int tt = t & 1;
      unsigned w0 = U[(2 * tt) * 2 + 0], w2 = U[(2 * tt + 1) * 2 + 0];
      unsigned w1 = U[(2 * tt) * 2 + 1], w3 = U[(2 * tt + 1) * 2 + 1];
      perm32swap(w0, w2);
      perm32swap(w1, w3);
      uint4v uu = {w0, w1, w2, w3};
      pfrag[t] = __builtin_bit_cast(bf16x8, uu);
    }
    __builtin_amdgcn_s_setprio(1);
#pragma unroll
    for (int t = 0; t < 4; ++t) {
      ot0 = __builtin_amdgcn_mfma_f32_32x32x16_bf16(vf0[2 * t], pfrag[t], ot0, 0, 0, 0);
      ot1 = __builtin_amdgcn_mfma_f32_32x32x16_bf16(vf0[2 * t + 1], pfrag[t], ot1, 0, 0, 0);
    }
    __builtin_amdgcn_s_setprio(0);

    bf16x8 vf1[8];
#pragma unroll
    for (int s = 0; s < 8; ++s)
      vf1[s] = *(const bf16x8*)&Vld[p][4096 + s * 512 + lane * 8];

#pragma unroll
    for (int r = 0; r < 16; ++r) {
      sa1[r] = __builtin_amdgcn_exp2f(sa1[r]);
      sb1[r] = __builtin_amdgcn_exp2f(sb1[r]);
    }
#pragma unroll
    for (int r = 0; r < 8; ++r)
      lacc[r] += (sa1[r] + sa1[r + 8]) + (sb1[r] + sb1[r + 8]);

#pragma unroll
    for (int s = 0; s < 4; ++s)
#pragma unroll
      for (int m2 = 0; m2 < 2; ++m2) {
        Ua[s * 2 + m2] = cvt_pk_bf16(sa1[4 * s + 2 * m2], sa1[4 * s + 2 * m2 + 1]);
        Ub[s * 2 + m2] = cvt_pk_bf16(sb1[4 * s + 2 * m2], sb1[4 * s + 2 * m2 + 1]);
      }
#pragma unroll
    for (int t = 0; t < 4; ++t) {
      const unsigned* U = (t < 2) ? Ua : Ub;
      const int tt = t & 1;
      unsigned w0 = U[(2 * tt) * 2 + 0], w2 = U[(2 * tt + 1) * 2 + 0];
      unsigned w1 = U[(2 * tt) * 2 + 1], w3 = U[(2 * tt + 1) * 2 + 1];
      perm32swap(w0, w2);
      perm32swap(w1, w3);
      uint4v uu = {w0, w1, w2, w3};
      pfrag[t] = __builtin_bit_cast(bf16x8, uu);
    }
    __builtin_amdgcn_s_setprio(1);
#pragma unroll
    for (int t = 0; t < 4; ++t) {
      ot0 = __builtin_amdgcn_mfma_f32_32x32x16_bf16(vf1[2 * t], pfrag[t], ot0, 0, 0, 0);
      ot1 = __builtin_amdgcn_mfma_f32_32x32x16_bf16(vf1[2 * t + 1], pfrag[t], ot1, 0, 0, 0);
    }
    __builtin_amdgcn_s_setprio(0);
  };

  stage(0, 0);
  __syncthreads();

  for (int ph = 0; ph < 16; ++ph) {
    const int p = ph & 1;
    if (ph < 15) stage(p ^ 1, ph + 1);
    compute(p);
    __syncthreads();
  }

  float lsum = ((lacc[0] + lacc[1]) + (lacc[2] + lacc[3])) +
               ((lacc[4] + lacc[5]) + (lacc[6] + lacc[7]));
  lsum += __shfl_xor(lsum, 32, 64);
  const float inv = 1.0f / lsum;

  const int b = bh >> 4, h = bh & 15;
  u16* Ao = AO + ((size_t)(b * 2048 + q0 + lq)) * 1024 + h * 64;
#pragma unroll
  for (int s = 0; s < 4; ++s) {
    {
      const int d = 8 * s + 4 * hi;
      ushort4v pk;
#pragma unroll
      for (int i = 0; i < 4; ++i) pk[i] = f2bf(ot0[4 * s + i] * inv);
      *(ushort4v*)(Ao + d) = pk;
    }
    {
      const int d = 32 + 8 * s + 4 * hi;
      ushort4v pk;
#pragma unroll
      for (int i = 0; i < 4; ++i) pk[i] = f2bf(ot1[4 * s + i] * inv);
      *(ushort4v*)(Ao + d) = pk;
    }
  }
}

// ---------------- launch ----------------
extern "C" void kernel_launch(void* const* d_in, const int* in_sizes, int n_in,
                              void* d_out, int out_size, void* d_ws, size_t ws_size,
                              hipStream_t stream) {
  const float* x = (const float*)d_in[0];
  const float* w_qkv = (const float*)d_in[1];
  const float* b_qkv = (const float*)d_in[2];
  const float* w_proj = (const float*)d_in[3];
  const float* b_proj = (const float*)d_in[4];
  float* out = (float*)d_out;

  char* ws = (char*)d_ws;
  u16* xb = (u16*)(ws);                          // 8 MiB  [4096][1024]
  u16* wqT = (u16*)(ws + (8ull << 20));          // 6 MiB  [3072][1024]
  u16* wpT = (u16*)(ws + (14ull << 20));         // 2 MiB  [1024][1024]
  u16* Qb = (u16*)(ws + (16ull << 20));          // 8 MiB  [32][2048][64]
  u16* Kp = (u16*)(ws + (24ull << 20));          // 8 MiB  packed frags
  u16* Vp = (u16*)(ws + (32ull << 20));          // 8 MiB  packed frags
  u16* AO = (u16*)(ws + (40ull << 20));          // 8 MiB  [4096][1024]

  cvt_bf16<<<dim3(2048), dim3(256), 0, stream>>>(x, xb, 4194304);
  trans_w<<<dim3(16, 48), dim3(256), 0, stream>>>(w_qkv, wqT, 1024, 3072);
  trans_w<<<dim3(16, 16), dim3(256), 0, stream>>>(w_proj, wpT, 1024, 1024);
  gemm256_qkv<<<dim3(192), dim3(512), 0, stream>>>(xb, wqT, b_qkv, Qb, Kp, Vp);
  flash_attn12<<<dim3(512), dim3(256), 0, stream>>>(Qb, Kp, Vp, AO);
  gemm_proj<<<dim3(32, 8), dim3(256), 0, stream>>>(AO, wpT, 4096, 1024, 1024,
                                                   b_proj, out);
}

// Round 16
// 106.069 us; speedup vs baseline: 1.0580x; 1.0580x over previous
//
#include <hip/hip_runtime.h>

// Requires ws_size >= 48 MiB.
typedef short bf16x8 __attribute__((ext_vector_type(8)));
typedef float f32x4 __attribute__((ext_vector_type(4)));
typedef float f32x16 __attribute__((ext_vector_type(16)));
typedef unsigned short ushort8 __attribute__((ext_vector_type(8)));
typedef unsigned short ushort4v __attribute__((ext_vector_type(4)));
typedef unsigned int uint4v __attribute__((ext_vector_type(4)));
typedef unsigned short u16;

__device__ inline u16 f2bf(float f) {
  unsigned int u = __float_as_uint(f);
  u += 0x7fffu + ((u >> 16) & 1u);
  return (u16)(u >> 16);
}

__device__ inline unsigned cvt_pk_bf16(float lo, float hi2) {
  unsigned r;
  asm("v_cvt_pk_bf16_f32 %0, %1, %2" : "=v"(r) : "v"(lo), "v"(hi2));
  return r;
}

// NOTE: only safe with two DISTINCT live inputs (R5 bug: a==b coalesces).
__device__ inline void perm32swap(unsigned& a, unsigned& b) {
  asm("v_permlane32_swap_b32 %0, %1" : "+v"(a), "+v"(b));
}

__device__ inline void gload_lds16(const u16* g, u16* l) {
  __builtin_amdgcn_global_load_lds(
      (const __attribute__((address_space(1))) unsigned int*)g,
      (__attribute__((address_space(3))) unsigned int*)l, 16, 0, 0);
}

// ---------------- elementwise f32 -> bf16 ----------------
__global__ __launch_bounds__(256) void cvt_bf16(const float* __restrict__ in,
                                                u16* __restrict__ out, int n) {
  int i = (blockIdx.x * 256 + threadIdx.x) * 8;
  if (i >= n) return;
  float4 a = *(const float4*)(in + i);
  float4 b = *(const float4*)(in + i + 4);
  ushort8 o;
  o[0] = f2bf(a.x); o[1] = f2bf(a.y); o[2] = f2bf(a.z); o[3] = f2bf(a.w);
  o[4] = f2bf(b.x); o[5] = f2bf(b.y); o[6] = f2bf(b.z); o[7] = f2bf(b.w);
  *(ushort8*)(out + i) = o;
}

// ---------------- W[K][N] f32 -> Wt[N][K] bf16 ----------------
__global__ __launch_bounds__(256) void trans_w(const float* __restrict__ W,
                                               u16* __restrict__ Wt, int K, int N) {
  const int k0 = blockIdx.x * 64, n0 = blockIdx.y * 64;
  const int tx = threadIdx.x & 63, ty = threadIdx.x >> 6;
  __shared__ float t[64][65];
#pragma unroll
  for (int i = 0; i < 16; ++i) {
    int r = i * 4 + ty;
    t[r][tx] = W[(size_t)(k0 + r) * N + n0 + tx];
  }
  __syncthreads();
#pragma unroll
  for (int i = 0; i < 16; ++i) {
    int r = i * 4 + ty;
    Wt[(size_t)(n0 + r) * K + k0 + tx] = f2bf(t[tx][r]);
  }
}

// ------- QKV GEMM v3: 128^2 tile, BK=32, 32 KiB LDS -> 3 blocks/CU ---------
// Same proven 2-phase schedule (stage(next) -> MFMA -> barrier) but half the
// LDS: occupancy 2 -> 3 blocks/CU (12 waves/CU) so barrier/latency stalls of
// one block are filled by the others (m114 cross-wave overlap).
// Swizzle uses 3 row bits: slot' = lg ^ ((row>>1)&3) on 64-B rows -> 8
// consecutive rows hit 8 distinct 16-B granules (2-way residual = free).
// Epilogue: R13-verified fragment-packed Q/K/V scatter via 32 KiB LDS bounce.
__global__ __launch_bounds__(256, 2) void gemm_qkv(
    const u16* __restrict__ A, const u16* __restrict__ Bt,
    const float* __restrict__ bias, u16* __restrict__ Qb,
    u16* __restrict__ Kb, u16* __restrict__ Vb) {
  const int K = 1024;
  const int bm = blockIdx.x * 128;
  const int bn = blockIdx.y * 128;
  const int tid = threadIdx.x;
  const int wid = tid >> 6;
  const int lr = tid & 15;
  const int lg = (tid >> 4) & 3;
  const int wr = wid >> 1, wc = wid & 1;

  __shared__ u16 smem[16384];  // 32 KiB
  u16* Ab0 = smem;             // [128][32]
  u16* Ab1 = smem + 4096;
  u16* Bb0 = smem + 8192;
  u16* Bb1 = smem + 12288;

  f32x4 acc[4][4] = {};

  const int srow = tid >> 2;                            // 0..63
  const int scol = ((tid & 3) ^ ((srow >> 1) & 3)) * 8; // pre-swizzled source
  const u16* Ag = A + (size_t)bm * K;
  const u16* Bg = Bt + (size_t)bn * K;

  auto stage = [&](u16* Ad, u16* Bd, int kt) {
    const int kof = kt << 5;
    gload_lds16(Ag + (size_t)srow * K + kof + scol, Ad + tid * 8);
    gload_lds16(Ag + (size_t)(srow + 64) * K + kof + scol, Ad + 2048 + tid * 8);
    gload_lds16(Bg + (size_t)srow * K + kof + scol, Bd + tid * 8);
    gload_lds16(Bg + (size_t)(srow + 64) * K + kof + scol, Bd + 2048 + tid * 8);
  };

  stage(Ab0, Bb0, 0);
  __syncthreads();

  for (int kt = 0; kt < 32; ++kt) {
    const int p = kt & 1;
    const char* Ard = (const char*)(p ? Ab1 : Ab0);
    const char* Brd = (const char*)(p ? Bb1 : Bb0);
    bf16x8 af[4], bfr[4];
#pragma unroll
    for (int t = 0; t < 4; ++t) {
      const int ra = wr * 64 + t * 16 + lr;
      const int rb = wc * 64 + t * 16 + lr;
      af[t] = *(const bf16x8*)(Ard + ra * 64 + ((lg ^ ((ra >> 1) & 3)) * 16));
      bfr[t] = *(const bf16x8*)(Brd + rb * 64 + ((lg ^ ((rb >> 1) & 3)) * 16));
    }
    if (kt + 1 < 32) stage(p ? Ab0 : Ab1, p ? Bb0 : Bb1, kt + 1);
    __builtin_amdgcn_s_setprio(1);
#pragma unroll
    for (int mt = 0; mt < 4; ++mt)
#pragma unroll
      for (int nt = 0; nt < 4; ++nt)
        acc[mt][nt] = __builtin_amdgcn_mfma_f32_16x16x32_bf16(
            af[mt], bfr[nt], acc[mt][nt], 0, 0, 0);
    __builtin_amdgcn_s_setprio(0);
    __syncthreads();
  }

  // ---- epilogue (R13-verified): swizzled LDS bounce -> fragment-packed ----
  u16* T = smem;               // 32 KiB = full 128x128 bf16 tile
  const int which = bn >> 10;  // 0=Q, 1=K, 2=V

  if (which == 2) {
#pragma unroll
    for (int nt = 0; nt < 4; ++nt) {
      const int cl = wc * 64 + nt * 16 + lr;
      const float bv = bias[bn + cl];
#pragma unroll
      for (int mt = 0; mt < 4; ++mt) {
        const int rlb = wr * 128 + mt * 32 + lg * 8;
        ushort4v pk;
#pragma unroll
        for (int r = 0; r < 4; ++r) pk[r] = f2bf(acc[mt][nt][r] + bv);
        *(ushort4v*)((char*)T + cl * 256 + (rlb ^ ((cl & 7) << 4))) = pk;
      }
    }
  } else {
    // Q gets 0.125 (1/sqrt(64)) * log2(e) so flash can use exp2 directly.
    const float sc = (which == 0) ? 0.18033688f : 1.0f;
#pragma unroll
    for (int mt = 0; mt < 4; ++mt) {
      const int rl0 = wr * 64 + mt * 16 + lg * 4;
#pragma unroll
      for (int nt = 0; nt < 4; ++nt) {
        const int cl = wc * 64 + nt * 16 + lr;
        const float bv = bias[bn + cl];
#pragma unroll
        for (int r = 0; r < 4; ++r) {
          const int rl = rl0 + r;
          *(u16*)((char*)T + rl * 256 + ((cl * 2) ^ ((rl & 7) << 4))) =
              f2bf((acc[mt][nt][r] + bv) * sc);
        }
      }
    }
  }
  __syncthreads();

  const int b = bm >> 11;
  const int nbase = bm & 2047;
  if (which == 0) {
#pragma unroll
    for (int i = 0; i < 8; ++i) {
      const int c = i * 256 + tid;
      const int rl = c >> 4, dch = c & 15;
      uint4v v =
          *(const uint4v*)((const char*)T + rl * 256 + ((dch * 16) ^ ((rl & 7) << 4)));
      const int bh = b * 16 + (bn >> 6) + (dch >> 3);
      *(uint4v*)(Qb + ((size_t)bh * 2048 + nbase + rl) * 64 + (dch & 7) * 8) = v;
    }
  } else if (which == 1) {
#pragma unroll
    for (int i = 0; i < 8; ++i) {
      const int c = i * 256 + tid;
      const int lane = c & 63, s = (c >> 6) & 7, ktl = (c >> 9) & 1, hl = c >> 10;
      const int lq = lane & 31, hi2 = lane >> 5;
      const int rl = ktl * 64 + (s & 1) * 32 + lq;
      const int cc = hl * 128 + (s >> 1) * 32 + hi2 * 16;
      uint4v v = *(const uint4v*)((const char*)T + rl * 256 + (cc ^ ((rl & 7) << 4)));
      const int bh = b * 16 + ((bn & 1023) >> 6) + hl;
      const int kt2 = (nbase >> 6) + ktl;
      *(uint4v*)(Kb + ((((size_t)bh * 32 + kt2) * 8 + s) * 64 + lane) * 8) = v;
    }
  } else {
#pragma unroll
    for (int i = 0; i < 8; ++i) {
      const int c = i * 256 + tid;
      const int lane = c & 63, s = (c >> 6) & 7, ktl = (c >> 9) & 1, hl = c >> 10;
      const int lq = lane & 31, hi2 = lane >> 5;
      const int cl = hl * 64 + (s & 1) * 32 + lq;
      const int cc = ktl * 128 + (s >> 1) * 32 + hi2 * 16;
      uint4v v = *(const uint4v*)((const char*)T + cl * 256 + (cc ^ ((cl & 7) << 4)));
      const int bh = b * 16 + ((bn & 1023) >> 6) + hl;
      const int kt2 = (nbase >> 6) + ktl;
      *(uint4v*)(Vb + ((((size_t)bh * 32 + kt2) * 8 + s) * 64 + lane) * 8) = v;
    }
  }
}

// ---------------- proj GEMM: 128^2 tile, BK=64, 2-phase (unchanged) ---------
__global__ __launch_bounds__(256) void gemm_proj(
    const u16* __restrict__ A, const u16* __restrict__ Bt, int M, int N, int K,
    const float* __restrict__ bias, float* __restrict__ outF) {
  const int bm = blockIdx.x * 128;
  const int bn = blockIdx.y * 128;
  const int tid = threadIdx.x;
  const int wid = tid >> 6;
  const int lr = tid & 15;
  const int lg = (tid >> 4) & 3;
  const int wr = wid >> 1, wc = wid & 1;

  __shared__ u16 smem[32768];
  u16* Ab0 = smem;
  u16* Ab1 = smem + 8192;
  u16* Bb0 = smem + 16384;
  u16* Bb1 = smem + 24576;

  f32x4 acc[4][4] = {};

  const int rowi = tid >> 3;
  const int sslot = ((tid & 7) ^ (rowi & 7)) * 8;
  const u16* Ag = A + (size_t)bm * K;
  const u16* Bg = Bt + (size_t)bn * K;
  const int nkt = K >> 6;

  auto stage = [&](u16* Ad, u16* Bd, int kt) {
    const int kof = kt << 6;
#pragma unroll
    for (int i = 0; i < 4; ++i) {
      const int row = i * 32 + rowi;
      gload_lds16(Ag + (size_t)row * K + kof + sslot, Ad + (i * 32 + wid * 8) * 64);
      gload_lds16(Bg + (size_t)row * K + kof + sslot, Bd + (i * 32 + wid * 8) * 64);
    }
  };

  stage(Ab0, Bb0, 0);
  __syncthreads();

  for (int kt = 0; kt < nkt; ++kt) {
    const int p = kt & 1;
    const char* Ard = (const char*)(p ? Ab1 : Ab0);
    const char* Brd = (const char*)(p ? Bb1 : Bb0);
    bf16x8 af[4], bfr[4];
#pragma unroll
    for (int t = 0; t < 4; ++t) {
      const int ra = wr * 64 + t * 16 + lr;
      const int rb = wc * 64 + t * 16 + lr;
      af[t] = *(const bf16x8*)(Ard + ra * 128 + ((lg * 16) ^ ((ra & 7) << 4)));
      bfr[t] = *(const bf16x8*)(Brd + rb * 128 + ((lg * 16) ^ ((rb & 7) << 4)));
    }
    if (kt + 1 < nkt) stage(p ? Ab0 : Ab1, p ? Bb0 : Bb1, kt + 1);
    __builtin_amdgcn_s_setprio(1);
#pragma unroll
    for (int mt = 0; mt < 4; ++mt)
#pragma unroll
      for (int nt = 0; nt < 4; ++nt)
        acc[mt][nt] = __builtin_amdgcn_mfma_f32_16x16x32_bf16(
            af[mt], bfr[nt], acc[mt][nt], 0, 0, 0);
    __builtin_amdgcn_s_setprio(0);
#pragma unroll
    for (int t = 0; t < 4; ++t) {
      const int ra = wr * 64 + t * 16 + lr;
      const int rb = wc * 64 + t * 16 + lr;
      af[t] = *(const bf16x8*)(Ard + ra * 128 + ((64 + lg * 16) ^ ((ra & 7) << 4)));
      bfr[t] = *(const bf16x8*)(Brd + rb * 128 + ((64 + lg * 16) ^ ((rb & 7) << 4)));
    }
    __builtin_amdgcn_s_setprio(1);
#pragma unroll
    for (int mt = 0; mt < 4; ++mt)
#pragma unroll
      for (int nt = 0; nt < 4; ++nt)
        acc[mt][nt] = __builtin_amdgcn_mfma_f32_16x16x32_bf16(
            af[mt], bfr[nt], acc[mt][nt], 0, 0, 0);
    __builtin_amdgcn_s_setprio(0);
    __syncthreads();
  }

#pragma unroll
  for (int mt = 0; mt < 4; ++mt) {
    const int row0 = bm + wr * 64 + mt * 16 + lg * 4;
#pragma unroll
    for (int nt = 0; nt < 4; ++nt) {
      const int col = bn + wc * 64 + nt * 16 + lr;
      const float bv = bias[col];
#pragma unroll
      for (int r = 0; r < 4; ++r)
        outF[(size_t)(row0 + r) * N + col] = acc[mt][nt][r] + bv;
    }
  }
}

// ------- flash attention v13: 8-wave split-KV + LDS-shared K/V tiles --------
// v10's proven dataflow x2 occupancy: 512-thread blocks; waves 0-3 cover 4
// q-tiles x KV[0,1024), waves 4-7 same q-tiles x KV[1024,2048). Each phase
// stages one KVBLK=64 tile per half (32 KB/phase, double-buffered, 64 KiB
// total -> 2 blocks/CU = 16 waves/CU, 2x v12). No-max softmax (P=exp2(S'),
// native v_exp); exact merge O=(Oa+Ob)/(la+lb) via reused LDS (R8-proven).
// Grid: 32 bh x 16 qt = 512 blocks.
__global__ __launch_bounds__(512, 2) void flash_attn13(const u16* __restrict__ Qb,
                                                       const u16* __restrict__ Kp,
                                                       const u16* __restrict__ Vp,
                                                       u16* __restrict__ AO) {
  const int bh = blockIdx.x & 31;
  const int qt = blockIdx.x >> 5;   // 0..15
  const int tid = threadIdx.x;
  const int w = tid >> 6;
  const int qw = w & 3;
  const int half = w >> 2;
  const int lane = tid & 63;
  const int lq = lane & 31;
  const int hi = lane >> 5;
  const int q0 = qt * 128 + qw * 32;

  __shared__ u16 smem[32768];  // 64 KiB: K tiles [buf*2+half] 4x8KB, V at +16384

  const u16* Qg = Qb + ((size_t)bh * 2048 + q0 + lq) * 64 + 8 * hi;
  bf16x8 qf[4];
#pragma unroll
  for (int t = 0; t < 4; ++t) qf[t] = *(const bf16x8*)(Qg + 16 * t);

  const u16* Kg = Kp + (size_t)bh * (32 * 4096);
  const u16* Vg = Vp + (size_t)bh * (32 * 4096);

  f32x16 ot0 = {}, ot1 = {};
  float lacc[8] = {};

  // stage tile ph for BOTH halves (512 threads x 16 B = one 8 KB region each)
  auto stage = [&](int buf, int ph) {
#pragma unroll
    for (int h = 0; h < 2; ++h) {
      const size_t src = (size_t)(h * 16 + ph) * 4096;
      gload_lds16(Kg + src + tid * 8, smem + (buf * 2 + h) * 4096 + tid * 8);
      gload_lds16(Vg + src + tid * 8, smem + 16384 + (buf * 2 + h) * 4096 + tid * 8);
    }
  };

  auto compute = [&](int buf) {
    const u16* Kl = smem + (buf * 2 + half) * 4096;
    const u16* Vl = smem + 16384 + (buf * 2 + half) * 4096;

    bf16x8 kf[8];
#pragma unroll
    for (int s = 0; s < 8; ++s)
      kf[s] = *(const bf16x8*)&Kl[s * 512 + lane * 8];

    f32x16 sa = {}, sb = {};
    __builtin_amdgcn_s_setprio(1);
#pragma unroll
    for (int t = 0; t < 4; ++t) {
      sa = __builtin_amdgcn_mfma_f32_32x32x16_bf16(kf[2 * t], qf[t], sa, 0, 0, 0);
      sb = __builtin_amdgcn_mfma_f32_32x32x16_bf16(kf[2 * t + 1], qf[t], sb, 0, 0, 0);
    }
    __builtin_amdgcn_s_setprio(0);

    bf16x8 vf[8];
#pragma unroll
    for (int s = 0; s < 8; ++s)
      vf[s] = *(const bf16x8*)&Vl[s * 512 + lane * 8];

#pragma unroll
    for (int r = 0; r < 16; ++r) {
      sa[r] = __builtin_amdgcn_exp2f(sa[r]);
      sb[r] = __builtin_amdgcn_exp2f(sb[r]);
    }
#pragma unroll
    for (int r = 0; r < 8; ++r)
      lacc[r] += (sa[r] + sa[r + 8]) + (sb[r] + sb[r + 8]);

    unsigned Ua[8], Ub[8];
#pragma unroll
    for (int s = 0; s < 4; ++s)
#pragma unroll
      for (int m2 = 0; m2 < 2; ++m2) {
        Ua[s * 2 + m2] = cvt_pk_bf16(sa[4 * s + 2 * m2], sa[4 * s + 2 * m2 + 1]);
        Ub[s * 2 + m2] = cvt_pk_bf16(sb[4 * s + 2 * m2], sb[4 * s + 2 * m2 + 1]);
      }
    bf16x8 pfrag[4];
#pragma unroll
    for (int t = 0; t < 4; ++t) {
      const unsigned* U = (t < 2) ? Ua : Ub;
      const int tt = t & 1;
      unsigned w0 = U[(2 * tt) * 2 + 0], w2 = U[(2 * tt + 1) * 2 + 0];
      unsigned w1 = U[(2 * tt) * 2 + 1], w3 = U[(2 * tt + 1) * 2 + 1];
      perm32swap(w0, w2);
      perm32swap(w1, w3);
      uint4v uu = {w0, w1, w2, w3};
      pfrag[t] = __builtin_bit_cast(bf16x8, uu);
    }

    __builtin_amdgcn_s_setprio(1);
#pragma unroll
    for (int t = 0; t < 4; ++t) {
      ot0 = __builtin_amdgcn_mfma_f32_32x32x16_bf16(vf[2 * t], pfrag[t], ot0, 0, 0, 0);
      ot1 = __builtin_amdgcn_mfma_f32_32x32x16_bf16(vf[2 * t + 1], pfrag[t], ot1, 0, 0, 0);
    }
    __builtin_amdgcn_s_setprio(0);
  };

  stage(0, 0);
  __syncthreads();

  for (int ph = 0; ph < 16; ++ph) {
    const int p = ph & 1;
    if (ph < 15) stage(p ^ 1, ph + 1);
    compute(p);
    __syncthreads();
  }

  // per-lane row-sum for this half
  float lsum = ((lacc[0] + lacc[1]) + (lacc[2] + lacc[3])) +
               ((lacc[4] + lacc[5]) + (lacc[6] + lacc[7]));
  lsum += __shfl_xor(lsum, 32, 64);

  // ---- exact split-KV merge (no-max): O = (Oa+Ob)/(la+lb); LDS reused ----
  float* mp = (float*)smem + ((size_t)qw * 64 + lane) * 33;
  if (half == 1) {
#pragma unroll
    for (int r = 0; r < 16; ++r) mp[r] = ot0[r];
#pragma unroll
    for (int r = 0; r < 16; ++r) mp[16 + r] = ot1[r];
    mp[32] = lsum;
  }
  __syncthreads();
  if (half == 1) return;

  const float inv = 1.0f / (lsum + mp[32]);
#pragma unroll
  for (int r = 0; r < 16; ++r) ot0[r] = (ot0[r] + mp[r]) * inv;
#pragma unroll
  for (int r = 0; r < 16; ++r) ot1[r] = (ot1[r] + mp[16 + r]) * inv;

  const int b = bh >> 4, h = bh & 15;
  u16* Ao = AO + ((size_t)(b * 2048 + q0 + lq)) * 1024 + h * 64;
#pragma unroll
  for (int s = 0; s < 4; ++s) {
    {
      const int d = 8 * s + 4 * hi;
      ushort4v pk;
#pragma unroll
      for (int i = 0; i < 4; ++i) pk[i] = f2bf(ot0[4 * s + i]);
      *(ushort4v*)(Ao + d) = pk;
    }
    {
      const int d = 32 + 8 * s + 4 * hi;
      ushort4v pk;
#pragma unroll
      for (int i = 0; i < 4; ++i) pk[i] = f2bf(ot1[4 * s + i]);
      *(ushort4v*)(Ao + d) = pk;
    }
  }
}

// ---------------- launch ----------------
extern "C" void kernel_launch(void* const* d_in, const int* in_sizes, int n_in,
                              void* d_out, int out_size, void* d_ws, size_t ws_size,
                              hipStream_t stream) {
  const float* x = (const float*)d_in[0];
  const float* w_qkv = (const float*)d_in[1];
  const float* b_qkv = (const float*)d_in[2];
  const float* w_proj = (const float*)d_in[3];
  const float* b_proj = (const float*)d_in[4];
  float* out = (float*)d_out;

  char* ws = (char*)d_ws;
  u16* xb = (u16*)(ws);                          // 8 MiB  [4096][1024]
  u16* wqT = (u16*)(ws + (8ull << 20));          // 6 MiB  [3072][1024]
  u16* wpT = (u16*)(ws + (14ull << 20));         // 2 MiB  [1024][1024]
  u16* Qb = (u16*)(ws + (16ull << 20));          // 8 MiB  [32][2048][64]
  u16* Kp = (u16*)(ws + (24ull << 20));          // 8 MiB  packed frags
  u16* Vp = (u16*)(ws + (32ull << 20));          // 8 MiB  packed frags
  u16* AO = (u16*)(ws + (40ull << 20));          // 8 MiB  [4096][1024]

  cvt_bf16<<<dim3(2048), dim3(256), 0, stream>>>(x, xb, 4194304);
  trans_w<<<dim3(16, 48), dim3(256), 0, stream>>>(w_qkv, wqT, 1024, 3072);
  trans_w<<<dim3(16, 16), dim3(256), 0, stream>>>(w_proj, wpT, 1024, 1024);
  gemm_qkv<<<dim3(32, 24), dim3(256), 0, stream>>>(xb, wqT, b_qkv, Qb, Kp, Vp);
  flash_attn13<<<dim3(512), dim3(512), 0, stream>>>(Qb, Kp, Vp, AO);
  gemm_proj<<<dim3(32, 8), dim3(256), 0, stream>>>(AO, wpT, 4096, 1024, 1024,
                                                   b_proj, out);
}

// Round 17
// 103.118 us; speedup vs baseline: 1.0883x; 1.0286x over previous
//
#include <hip/hip_runtime.h>

// Requires ws_size >= 48 MiB.
typedef short bf16x8 __attribute__((ext_vector_type(8)));
typedef float f32x4 __attribute__((ext_vector_type(4)));
typedef float f32x16 __attribute__((ext_vector_type(16)));
typedef unsigned short ushort8 __attribute__((ext_vector_type(8)));
typedef unsigned short ushort4v __attribute__((ext_vector_type(4)));
typedef unsigned int uint4v __attribute__((ext_vector_type(4)));
typedef unsigned short u16;

__device__ inline u16 f2bf(float f) {
  unsigned int u = __float_as_uint(f);
  u += 0x7fffu + ((u >> 16) & 1u);
  return (u16)(u >> 16);
}

__device__ inline unsigned cvt_pk_bf16(float lo, float hi2) {
  unsigned r;
  asm("v_cvt_pk_bf16_f32 %0, %1, %2" : "=v"(r) : "v"(lo), "v"(hi2));
  return r;
}

// NOTE: only safe with two DISTINCT live inputs (R5 bug: a==b coalesces).
__device__ inline void perm32swap(unsigned& a, unsigned& b) {
  asm("v_permlane32_swap_b32 %0, %1" : "+v"(a), "+v"(b));
}

__device__ inline void gload_lds16(const u16* g, u16* l) {
  __builtin_amdgcn_global_load_lds(
      (const __attribute__((address_space(1))) unsigned int*)g,
      (__attribute__((address_space(3))) unsigned int*)l, 16, 0, 0);
}

// ---- fused pre-pass: x->bf16 cvt (blocks 0..2047), w_qkv transpose ----
// ---- (2048..2815), w_proj transpose (2816..3071). Bodies identical ----
// ---- to the separately-verified cvt_bf16 / trans_w kernels.        ----
__global__ __launch_bounds__(256) void fused_pre(
    const float* __restrict__ x, u16* __restrict__ xb,
    const float* __restrict__ w_qkv, u16* __restrict__ wqT,
    const float* __restrict__ w_proj, u16* __restrict__ wpT) {
  const int bid = blockIdx.x;
  __shared__ float tl[64][65];

  if (bid < 2048) {
    const int i = (bid * 256 + threadIdx.x) * 8;
    float4 a = *(const float4*)(x + i);
    float4 b = *(const float4*)(x + i + 4);
    ushort8 o;
    o[0] = f2bf(a.x); o[1] = f2bf(a.y); o[2] = f2bf(a.z); o[3] = f2bf(a.w);
    o[4] = f2bf(b.x); o[5] = f2bf(b.y); o[6] = f2bf(b.z); o[7] = f2bf(b.w);
    *(ushort8*)(xb + i) = o;
    return;
  }

  const float* W;
  u16* Wt;
  int N, t;
  if (bid < 2816) {
    W = w_qkv; Wt = wqT; N = 3072; t = bid - 2048;
  } else {
    W = w_proj; Wt = wpT; N = 1024; t = bid - 2816;
  }
  const int K = 1024;
  const int k0 = (t & 15) * 64;
  const int n0 = (t >> 4) * 64;
  const int tx = threadIdx.x & 63, ty = threadIdx.x >> 6;
#pragma unroll
  for (int i = 0; i < 16; ++i) {
    int r = i * 4 + ty;
    tl[r][tx] = W[(size_t)(k0 + r) * N + n0 + tx];
  }
  __syncthreads();
#pragma unroll
  for (int i = 0; i < 16; ++i) {
    int r = i * 4 + ty;
    Wt[(size_t)(n0 + r) * K + k0 + tx] = f2bf(tl[tx][r]);
  }
}

// ------- QKV GEMM v3: 128^2 tile, BK=32, 32 KiB LDS (unchanged R16) --------
__global__ __launch_bounds__(256, 2) void gemm_qkv(
    const u16* __restrict__ A, const u16* __restrict__ Bt,
    const float* __restrict__ bias, u16* __restrict__ Qb,
    u16* __restrict__ Kb, u16* __restrict__ Vb) {
  const int K = 1024;
  const int bm = blockIdx.x * 128;
  const int bn = blockIdx.y * 128;
  const int tid = threadIdx.x;
  const int wid = tid >> 6;
  const int lr = tid & 15;
  const int lg = (tid >> 4) & 3;
  const int wr = wid >> 1, wc = wid & 1;

  __shared__ u16 smem[16384];  // 32 KiB
  u16* Ab0 = smem;
  u16* Ab1 = smem + 4096;
  u16* Bb0 = smem + 8192;
  u16* Bb1 = smem + 12288;

  f32x4 acc[4][4] = {};

  const int srow = tid >> 2;
  const int scol = ((tid & 3) ^ ((srow >> 1) & 3)) * 8;
  const u16* Ag = A + (size_t)bm * K;
  const u16* Bg = Bt + (size_t)bn * K;

  auto stage = [&](u16* Ad, u16* Bd, int kt) {
    const int kof = kt << 5;
    gload_lds16(Ag + (size_t)srow * K + kof + scol, Ad + tid * 8);
    gload_lds16(Ag + (size_t)(srow + 64) * K + kof + scol, Ad + 2048 + tid * 8);
    gload_lds16(Bg + (size_t)srow * K + kof + scol, Bd + tid * 8);
    gload_lds16(Bg + (size_t)(srow + 64) * K + kof + scol, Bd + 2048 + tid * 8);
  };

  stage(Ab0, Bb0, 0);
  __syncthreads();

  for (int kt = 0; kt < 32; ++kt) {
    const int p = kt & 1;
    const char* Ard = (const char*)(p ? Ab1 : Ab0);
    const char* Brd = (const char*)(p ? Bb1 : Bb0);
    bf16x8 af[4], bfr[4];
#pragma unroll
    for (int t = 0; t < 4; ++t) {
      const int ra = wr * 64 + t * 16 + lr;
      const int rb = wc * 64 + t * 16 + lr;
      af[t] = *(const bf16x8*)(Ard + ra * 64 + ((lg ^ ((ra >> 1) & 3)) * 16));
      bfr[t] = *(const bf16x8*)(Brd + rb * 64 + ((lg ^ ((rb >> 1) & 3)) * 16));
    }
    if (kt + 1 < 32) stage(p ? Ab0 : Ab1, p ? Bb0 : Bb1, kt + 1);
    __builtin_amdgcn_s_setprio(1);
#pragma unroll
    for (int mt = 0; mt < 4; ++mt)
#pragma unroll
      for (int nt = 0; nt < 4; ++nt)
        acc[mt][nt] = __builtin_amdgcn_mfma_f32_16x16x32_bf16(
            af[mt], bfr[nt], acc[mt][nt], 0, 0, 0);
    __builtin_amdgcn_s_setprio(0);
    __syncthreads();
  }

  u16* T = smem;
  const int which = bn >> 10;

  if (which == 2) {
#pragma unroll
    for (int nt = 0; nt < 4; ++nt) {
      const int cl = wc * 64 + nt * 16 + lr;
      const float bv = bias[bn + cl];
#pragma unroll
      for (int mt = 0; mt < 4; ++mt) {
        const int rlb = wr * 128 + mt * 32 + lg * 8;
        ushort4v pk;
#pragma unroll
        for (int r = 0; r < 4; ++r) pk[r] = f2bf(acc[mt][nt][r] + bv);
        *(ushort4v*)((char*)T + cl * 256 + (rlb ^ ((cl & 7) << 4))) = pk;
      }
    }
  } else {
    const float sc = (which == 0) ? 0.18033688f : 1.0f;
#pragma unroll
    for (int mt = 0; mt < 4; ++mt) {
      const int rl0 = wr * 64 + mt * 16 + lg * 4;
#pragma unroll
      for (int nt = 0; nt < 4; ++nt) {
        const int cl = wc * 64 + nt * 16 + lr;
        const float bv = bias[bn + cl];
#pragma unroll
        for (int r = 0; r < 4; ++r) {
          const int rl = rl0 + r;
          *(u16*)((char*)T + rl * 256 + ((cl * 2) ^ ((rl & 7) << 4))) =
              f2bf((acc[mt][nt][r] + bv) * sc);
        }
      }
    }
  }
  __syncthreads();

  const int b = bm >> 11;
  const int nbase = bm & 2047;
  if (which == 0) {
#pragma unroll
    for (int i = 0; i < 8; ++i) {
      const int c = i * 256 + tid;
      const int rl = c >> 4, dch = c & 15;
      uint4v v =
          *(const uint4v*)((const char*)T + rl * 256 + ((dch * 16) ^ ((rl & 7) << 4)));
      const int bh = b * 16 + (bn >> 6) + (dch >> 3);
      *(uint4v*)(Qb + ((size_t)bh * 2048 + nbase + rl) * 64 + (dch & 7) * 8) = v;
    }
  } else if (which == 1) {
#pragma unroll
    for (int i = 0; i < 8; ++i) {
      const int c = i * 256 + tid;
      const int lane = c & 63, s = (c >> 6) & 7, ktl = (c >> 9) & 1, hl = c >> 10;
      const int lq = lane & 31, hi2 = lane >> 5;
      const int rl = ktl * 64 + (s & 1) * 32 + lq;
      const int cc = hl * 128 + (s >> 1) * 32 + hi2 * 16;
      uint4v v = *(const uint4v*)((const char*)T + rl * 256 + (cc ^ ((rl & 7) << 4)));
      const int bh = b * 16 + ((bn & 1023) >> 6) + hl;
      const int kt2 = (nbase >> 6) + ktl;
      *(uint4v*)(Kb + ((((size_t)bh * 32 + kt2) * 8 + s) * 64 + lane) * 8) = v;
    }
  } else {
#pragma unroll
    for (int i = 0; i < 8; ++i) {
      const int c = i * 256 + tid;
      const int lane = c & 63, s = (c >> 6) & 7, ktl = (c >> 9) & 1, hl = c >> 10;
      const int lq = lane & 31, hi2 = lane >> 5;
      const int cl = hl * 64 + (s & 1) * 32 + lq;
      const int cc = ktl * 128 + (s >> 1) * 32 + hi2 * 16;
      uint4v v = *(const uint4v*)((const char*)T + cl * 256 + (cc ^ ((cl & 7) << 4)));
      const int bh = b * 16 + ((bn & 1023) >> 6) + hl;
      const int kt2 = (nbase >> 6) + ktl;
      *(uint4v*)(Vb + ((((size_t)bh * 32 + kt2) * 8 + s) * 64 + lane) * 8) = v;
    }
  }
}

// ---------------- proj GEMM: 128^2 tile, BK=64, 2-phase (unchanged) ---------
__global__ __launch_bounds__(256) void gemm_proj(
    const u16* __restrict__ A, const u16* __restrict__ Bt, int M, int N, int K,
    const float* __restrict__ bias, float* __restrict__ outF) {
  const int bm = blockIdx.x * 128;
  const int bn = blockIdx.y * 128;
  const int tid = threadIdx.x;
  const int wid = tid >> 6;
  const int lr = tid & 15;
  const int lg = (tid >> 4) & 3;
  const int wr = wid >> 1, wc = wid & 1;

  __shared__ u16 smem[32768];
  u16* Ab0 = smem;
  u16* Ab1 = smem + 8192;
  u16* Bb0 = smem + 16384;
  u16* Bb1 = smem + 24576;

  f32x4 acc[4][4] = {};

  const int rowi = tid >> 3;
  const int sslot = ((tid & 7) ^ (rowi & 7)) * 8;
  const u16* Ag = A + (size_t)bm * K;
  const u16* Bg = Bt + (size_t)bn * K;
  const int nkt = K >> 6;

  auto stage = [&](u16* Ad, u16* Bd, int kt) {
    const int kof = kt << 6;
#pragma unroll
    for (int i = 0; i < 4; ++i) {
      const int row = i * 32 + rowi;
      gload_lds16(Ag + (size_t)row * K + kof + sslot, Ad + (i * 32 + wid * 8) * 64);
      gload_lds16(Bg + (size_t)row * K + kof + sslot, Bd + (i * 32 + wid * 8) * 64);
    }
  };

  stage(Ab0, Bb0, 0);
  __syncthreads();

  for (int kt = 0; kt < nkt; ++kt) {
    const int p = kt & 1;
    const char* Ard = (const char*)(p ? Ab1 : Ab0);
    const char* Brd = (const char*)(p ? Bb1 : Bb0);
    bf16x8 af[4], bfr[4];
#pragma unroll
    for (int t = 0; t < 4; ++t) {
      const int ra = wr * 64 + t * 16 + lr;
      const int rb = wc * 64 + t * 16 + lr;
      af[t] = *(const bf16x8*)(Ard + ra * 128 + ((lg * 16) ^ ((ra & 7) << 4)));
      bfr[t] = *(const bf16x8*)(Brd + rb * 128 + ((lg * 16) ^ ((rb & 7) << 4)));
    }
    if (kt + 1 < nkt) stage(p ? Ab0 : Ab1, p ? Bb0 : Bb1, kt + 1);
    __builtin_amdgcn_s_setprio(1);
#pragma unroll
    for (int mt = 0; mt < 4; ++mt)
#pragma unroll
      for (int nt = 0; nt < 4; ++nt)
        acc[mt][nt] = __builtin_amdgcn_mfma_f32_16x16x32_bf16(
            af[mt], bfr[nt], acc[mt][nt], 0, 0, 0);
    __builtin_amdgcn_s_setprio(0);
#pragma unroll
    for (int t = 0; t < 4; ++t) {
      const int ra = wr * 64 + t * 16 + lr;
      const int rb = wc * 64 + t * 16 + lr;
      af[t] = *(const bf16x8*)(Ard + ra * 128 + ((64 + lg * 16) ^ ((ra & 7) << 4)));
      bfr[t] = *(const bf16x8*)(Brd + rb * 128 + ((64 + lg * 16) ^ ((rb & 7) << 4)));
    }
    __builtin_amdgcn_s_setprio(1);
#pragma unroll
    for (int mt = 0; mt < 4; ++mt)
#pragma unroll
      for (int nt = 0; nt < 4; ++nt)
        acc[mt][nt] = __builtin_amdgcn_mfma_f32_16x16x32_bf16(
            af[mt], bfr[nt], acc[mt][nt], 0, 0, 0);
    __builtin_amdgcn_s_setprio(0);
    __syncthreads();
  }

#pragma unroll
  for (int mt = 0; mt < 4; ++mt) {
    const int row0 = bm + wr * 64 + mt * 16 + lg * 4;
#pragma unroll
    for (int nt = 0; nt < 4; ++nt) {
      const int col = bn + wc * 64 + nt * 16 + lr;
      const float bv = bias[col];
#pragma unroll
      for (int r = 0; r < 4; ++r)
        outF[(size_t)(row0 + r) * N + col] = acc[mt][nt][r] + bv;
    }
  }
}

// ------- flash attention v13: 8-wave split-KV + LDS-shared K/V (unchanged) --
__global__ __launch_bounds__(512, 2) void flash_attn13(const u16* __restrict__ Qb,
                                                       const u16* __restrict__ Kp,
                                                       const u16* __restrict__ Vp,
                                                       u16* __restrict__ AO) {
  const int bh = blockIdx.x & 31;
  const int qt = blockIdx.x >> 5;   // 0..15
  const int tid = threadIdx.x;
  const int w = tid >> 6;
  const int qw = w & 3;
  const int half = w >> 2;
  const int lane = tid & 63;
  const int lq = lane & 31;
  const int hi = lane >> 5;
  const int q0 = qt * 128 + qw * 32;

  __shared__ u16 smem[32768];  // 64 KiB

  const u16* Qg = Qb + ((size_t)bh * 2048 + q0 + lq) * 64 + 8 * hi;
  bf16x8 qf[4];
#pragma unroll
  for (int t = 0; t < 4; ++t) qf[t] = *(const bf16x8*)(Qg + 16 * t);

  const u16* Kg = Kp + (size_t)bh * (32 * 4096);
  const u16* Vg = Vp + (size_t)bh * (32 * 4096);

  f32x16 ot0 = {}, ot1 = {};
  float lacc[8] = {};

  auto stage = [&](int buf, int ph) {
#pragma unroll
    for (int h = 0; h < 2; ++h) {
      const size_t src = (size_t)(h * 16 + ph) * 4096;
      gload_lds16(Kg + src + tid * 8, smem + (buf * 2 + h) * 4096 + tid * 8);
      gload_lds16(Vg + src + tid * 8, smem + 16384 + (buf * 2 + h) * 4096 + tid * 8);
    }
  };

  auto compute = [&](int buf) {
    const u16* Kl = smem + (buf * 2 + half) * 4096;
    const u16* Vl = smem + 16384 + (buf * 2 + half) * 4096;

    bf16x8 kf[8];
#pragma unroll
    for (int s = 0; s < 8; ++s)
      kf[s] = *(const bf16x8*)&Kl[s * 512 + lane * 8];

    f32x16 sa = {}, sb = {};
    __builtin_amdgcn_s_setprio(1);
#pragma unroll
    for (int t = 0; t < 4; ++t) {
      sa = __builtin_amdgcn_mfma_f32_32x32x16_bf16(kf[2 * t], qf[t], sa, 0, 0, 0);
      sb = __builtin_amdgcn_mfma_f32_32x32x16_bf16(kf[2 * t + 1], qf[t], sb, 0, 0, 0);
    }
    __builtin_amdgcn_s_setprio(0);

    bf16x8 vf[8];
#pragma unroll
    for (int s = 0; s < 8; ++s)
      vf[s] = *(const bf16x8*)&Vl[s * 512 + lane * 8];

#pragma unroll
    for (int r = 0; r < 16; ++r) {
      sa[r] = __builtin_amdgcn_exp2f(sa[r]);
      sb[r] = __builtin_amdgcn_exp2f(sb[r]);
    }
#pragma unroll
    for (int r = 0; r < 8; ++r)
      lacc[r] += (sa[r] + sa[r + 8]) + (sb[r] + sb[r + 8]);

    unsigned Ua[8], Ub[8];
#pragma unroll
    for (int s = 0; s < 4; ++s)
#pragma unroll
      for (int m2 = 0; m2 < 2; ++m2) {
        Ua[s * 2 + m2] = cvt_pk_bf16(sa[4 * s + 2 * m2], sa[4 * s + 2 * m2 + 1]);
        Ub[s * 2 + m2] = cvt_pk_bf16(sb[4 * s + 2 * m2], sb[4 * s + 2 * m2 + 1]);
      }
    bf16x8 pfrag[4];
#pragma unroll
    for (int t = 0; t < 4; ++t) {
      const unsigned* U = (t < 2) ? Ua : Ub;
      const int tt = t & 1;
      unsigned w0 = U[(2 * tt) * 2 + 0], w2 = U[(2 * tt + 1) * 2 + 0];
      unsigned w1 = U[(2 * tt) * 2 + 1], w3 = U[(2 * tt + 1) * 2 + 1];
      perm32swap(w0, w2);
      perm32swap(w1, w3);
      uint4v uu = {w0, w1, w2, w3};
      pfrag[t] = __builtin_bit_cast(bf16x8, uu);
    }

    __builtin_amdgcn_s_setprio(1);
#pragma unroll
    for (int t = 0; t < 4; ++t) {
      ot0 = __builtin_amdgcn_mfma_f32_32x32x16_bf16(vf[2 * t], pfrag[t], ot0, 0, 0, 0);
      ot1 = __builtin_amdgcn_mfma_f32_32x32x16_bf16(vf[2 * t + 1], pfrag[t], ot1, 0, 0, 0);
    }
    __builtin_amdgcn_s_setprio(0);
  };

  stage(0, 0);
  __syncthreads();

  for (int ph = 0; ph < 16; ++ph) {
    const int p = ph & 1;
    if (ph < 15) stage(p ^ 1, ph + 1);
    compute(p);
    __syncthreads();
  }

  float lsum = ((lacc[0] + lacc[1]) + (lacc[2] + lacc[3])) +
               ((lacc[4] + lacc[5]) + (lacc[6] + lacc[7]));
  lsum += __shfl_xor(lsum, 32, 64);

  float* mp = (float*)smem + ((size_t)qw * 64 + lane) * 33;
  if (half == 1) {
#pragma unroll
    for (int r = 0; r < 16; ++r) mp[r] = ot0[r];
#pragma unroll
    for (int r = 0; r < 16; ++r) mp[16 + r] = ot1[r];
    mp[32] = lsum;
  }
  __syncthreads();
  if (half == 1) return;

  const float inv = 1.0f / (lsum + mp[32]);
#pragma unroll
  for (int r = 0; r < 16; ++r) ot0[r] = (ot0[r] + mp[r]) * inv;
#pragma unroll
  for (int r = 0; r < 16; ++r) ot1[r] = (ot1[r] + mp[16 + r]) * inv;

  const int b = bh >> 4, h = bh & 15;
  u16* Ao = AO + ((size_t)(b * 2048 + q0 + lq)) * 1024 + h * 64;
#pragma unroll
  for (int s = 0; s < 4; ++s) {
    {
      const int d = 8 * s + 4 * hi;
      ushort4v pk;
#pragma unroll
      for (int i = 0; i < 4; ++i) pk[i] = f2bf(ot0[4 * s + i]);
      *(ushort4v*)(Ao + d) = pk;
    }
    {
      const int d = 32 + 8 * s + 4 * hi;
      ushort4v pk;
#pragma unroll
      for (int i = 0; i < 4; ++i) pk[i] = f2bf(ot1[4 * s + i]);
      *(ushort4v*)(Ao + d) = pk;
    }
  }
}

// ---------------- launch ----------------
extern "C" void kernel_launch(void* const* d_in, const int* in_sizes, int n_in,
                              void* d_out, int out_size, void* d_ws, size_t ws_size,
                              hipStream_t stream) {
  const float* x = (const float*)d_in[0];
  const float* w_qkv = (const float*)d_in[1];
  const float* b_qkv = (const float*)d_in[2];
  const float* w_proj = (const float*)d_in[3];
  const float* b_proj = (const float*)d_in[4];
  float* out = (float*)d_out;

  char* ws = (char*)d_ws;
  u16* xb = (u16*)(ws);                          // 8 MiB  [4096][1024]
  u16* wqT = (u16*)(ws + (8ull << 20));          // 6 MiB  [3072][1024]
  u16* wpT = (u16*)(ws + (14ull << 20));         // 2 MiB  [1024][1024]
  u16* Qb = (u16*)(ws + (16ull << 20));          // 8 MiB  [32][2048][64]
  u16* Kp = (u16*)(ws + (24ull << 20));          // 8 MiB  packed frags
  u16* Vp = (u16*)(ws + (32ull << 20));          // 8 MiB  packed frags
  u16* AO = (u16*)(ws + (40ull << 20));          // 8 MiB  [4096][1024]

  fused_pre<<<dim3(3072), dim3(256), 0, stream>>>(x, xb, w_qkv, wqT, w_proj, wpT);
  gemm_qkv<<<dim3(32, 24), dim3(256), 0, stream>>>(xb, wqT, b_qkv, Qb, Kp, Vp);
  flash_attn13<<<dim3(512), dim3(512), 0, stream>>>(Qb, Kp, Vp, AO);
  gemm_proj<<<dim3(32, 8), dim3(256), 0, stream>>>(AO, wpT, 4096, 1024, 1024,
                                                   b_proj, out);
}

// Round 18
// 97.179 us; speedup vs baseline: 1.1548x; 1.0611x over previous
//
#include <hip/hip_runtime.h>

// Requires ws_size >= 48 MiB.
typedef short bf16x8 __attribute__((ext_vector_type(8)));
typedef float f32x4 __attribute__((ext_vector_type(4)));
typedef float f32x16 __attribute__((ext_vector_type(16)));
typedef unsigned short ushort8 __attribute__((ext_vector_type(8)));
typedef unsigned short ushort4v __attribute__((ext_vector_type(4)));
typedef unsigned int uint4v __attribute__((ext_vector_type(4)));
typedef unsigned short u16;

__device__ inline u16 f2bf(float f) {
  unsigned int u = __float_as_uint(f);
  u += 0x7fffu + ((u >> 16) & 1u);
  return (u16)(u >> 16);
}

__device__ inline unsigned cvt_pk_bf16(float lo, float hi2) {
  unsigned r;
  asm("v_cvt_pk_bf16_f32 %0, %1, %2" : "=v"(r) : "v"(lo), "v"(hi2));
  return r;
}

// NOTE: only safe with two DISTINCT live inputs (R5 bug: a==b coalesces).
__device__ inline void perm32swap(unsigned& a, unsigned& b) {
  asm("v_permlane32_swap_b32 %0, %1" : "+v"(a), "+v"(b));
}

__device__ inline void gload_lds16(const u16* g, u16* l) {
  __builtin_amdgcn_global_load_lds(
      (const __attribute__((address_space(1))) unsigned int*)g,
      (__attribute__((address_space(3))) unsigned int*)l, 16, 0, 0);
}

// ---- fused pre-pass (unchanged R17): cvt x (0..2047), w_qkv T (2048..2815),
// ---- w_proj T (2816..3071).
__global__ __launch_bounds__(256) void fused_pre(
    const float* __restrict__ x, u16* __restrict__ xb,
    const float* __restrict__ w_qkv, u16* __restrict__ wqT,
    const float* __restrict__ w_proj, u16* __restrict__ wpT) {
  const int bid = blockIdx.x;
  __shared__ float tl[64][65];

  if (bid < 2048) {
    const int i = (bid * 256 + threadIdx.x) * 8;
    float4 a = *(const float4*)(x + i);
    float4 b = *(const float4*)(x + i + 4);
    ushort8 o;
    o[0] = f2bf(a.x); o[1] = f2bf(a.y); o[2] = f2bf(a.z); o[3] = f2bf(a.w);
    o[4] = f2bf(b.x); o[5] = f2bf(b.y); o[6] = f2bf(b.z); o[7] = f2bf(b.w);
    *(ushort8*)(xb + i) = o;
    return;
  }

  const float* W;
  u16* Wt;
  int N, t;
  if (bid < 2816) {
    W = w_qkv; Wt = wqT; N = 3072; t = bid - 2048;
  } else {
    W = w_proj; Wt = wpT; N = 1024; t = bid - 2816;
  }
  const int K = 1024;
  const int k0 = (t & 15) * 64;
  const int n0 = (t >> 4) * 64;
  const int tx = threadIdx.x & 63, ty = threadIdx.x >> 6;
#pragma unroll
  for (int i = 0; i < 16; ++i) {
    int r = i * 4 + ty;
    tl[r][tx] = W[(size_t)(k0 + r) * N + n0 + tx];
  }
  __syncthreads();
#pragma unroll
  for (int i = 0; i < 16; ++i) {
    int r = i * 4 + ty;
    Wt[(size_t)(n0 + r) * K + k0 + tx] = f2bf(tl[tx][r]);
  }
}

// ------- QKV GEMM v3: 128^2 tile, BK=32, 32 KiB LDS (unchanged R16) --------
__global__ __launch_bounds__(256, 2) void gemm_qkv(
    const u16* __restrict__ A, const u16* __restrict__ Bt,
    const float* __restrict__ bias, u16* __restrict__ Qb,
    u16* __restrict__ Kb, u16* __restrict__ Vb) {
  const int K = 1024;
  const int bm = blockIdx.x * 128;
  const int bn = blockIdx.y * 128;
  const int tid = threadIdx.x;
  const int wid = tid >> 6;
  const int lr = tid & 15;
  const int lg = (tid >> 4) & 3;
  const int wr = wid >> 1, wc = wid & 1;

  __shared__ u16 smem[16384];  // 32 KiB
  u16* Ab0 = smem;
  u16* Ab1 = smem + 4096;
  u16* Bb0 = smem + 8192;
  u16* Bb1 = smem + 12288;

  f32x4 acc[4][4] = {};

  const int srow = tid >> 2;
  const int scol = ((tid & 3) ^ ((srow >> 1) & 3)) * 8;
  const u16* Ag = A + (size_t)bm * K;
  const u16* Bg = Bt + (size_t)bn * K;

  auto stage = [&](u16* Ad, u16* Bd, int kt) {
    const int kof = kt << 5;
    gload_lds16(Ag + (size_t)srow * K + kof + scol, Ad + tid * 8);
    gload_lds16(Ag + (size_t)(srow + 64) * K + kof + scol, Ad + 2048 + tid * 8);
    gload_lds16(Bg + (size_t)srow * K + kof + scol, Bd + tid * 8);
    gload_lds16(Bg + (size_t)(srow + 64) * K + kof + scol, Bd + 2048 + tid * 8);
  };

  stage(Ab0, Bb0, 0);
  __syncthreads();

  for (int kt = 0; kt < 32; ++kt) {
    const int p = kt & 1;
    const char* Ard = (const char*)(p ? Ab1 : Ab0);
    const char* Brd = (const char*)(p ? Bb1 : Bb0);
    bf16x8 af[4], bfr[4];
#pragma unroll
    for (int t = 0; t < 4; ++t) {
      const int ra = wr * 64 + t * 16 + lr;
      const int rb = wc * 64 + t * 16 + lr;
      af[t] = *(const bf16x8*)(Ard + ra * 64 + ((lg ^ ((ra >> 1) & 3)) * 16));
      bfr[t] = *(const bf16x8*)(Brd + rb * 64 + ((lg ^ ((rb >> 1) & 3)) * 16));
    }
    if (kt + 1 < 32) stage(p ? Ab0 : Ab1, p ? Bb0 : Bb1, kt + 1);
    __builtin_amdgcn_s_setprio(1);
#pragma unroll
    for (int mt = 0; mt < 4; ++mt)
#pragma unroll
      for (int nt = 0; nt < 4; ++nt)
        acc[mt][nt] = __builtin_amdgcn_mfma_f32_16x16x32_bf16(
            af[mt], bfr[nt], acc[mt][nt], 0, 0, 0);
    __builtin_amdgcn_s_setprio(0);
    __syncthreads();
  }

  u16* T = smem;
  const int which = bn >> 10;

  if (which == 2) {
#pragma unroll
    for (int nt = 0; nt < 4; ++nt) {
      const int cl = wc * 64 + nt * 16 + lr;
      const float bv = bias[bn + cl];
#pragma unroll
      for (int mt = 0; mt < 4; ++mt) {
        const int rlb = wr * 128 + mt * 32 + lg * 8;
        ushort4v pk;
#pragma unroll
        for (int r = 0; r < 4; ++r) pk[r] = f2bf(acc[mt][nt][r] + bv);
        *(ushort4v*)((char*)T + cl * 256 + (rlb ^ ((cl & 7) << 4))) = pk;
      }
    }
  } else {
    const float sc = (which == 0) ? 0.18033688f : 1.0f;
#pragma unroll
    for (int mt = 0; mt < 4; ++mt) {
      const int rl0 = wr * 64 + mt * 16 + lg * 4;
#pragma unroll
      for (int nt = 0; nt < 4; ++nt) {
        const int cl = wc * 64 + nt * 16 + lr;
        const float bv = bias[bn + cl];
#pragma unroll
        for (int r = 0; r < 4; ++r) {
          const int rl = rl0 + r;
          *(u16*)((char*)T + rl * 256 + ((cl * 2) ^ ((rl & 7) << 4))) =
              f2bf((acc[mt][nt][r] + bv) * sc);
        }
      }
    }
  }
  __syncthreads();

  const int b = bm >> 11;
  const int nbase = bm & 2047;
  if (which == 0) {
#pragma unroll
    for (int i = 0; i < 8; ++i) {
      const int c = i * 256 + tid;
      const int rl = c >> 4, dch = c & 15;
      uint4v v =
          *(const uint4v*)((const char*)T + rl * 256 + ((dch * 16) ^ ((rl & 7) << 4)));
      const int bh = b * 16 + (bn >> 6) + (dch >> 3);
      *(uint4v*)(Qb + ((size_t)bh * 2048 + nbase + rl) * 64 + (dch & 7) * 8) = v;
    }
  } else if (which == 1) {
#pragma unroll
    for (int i = 0; i < 8; ++i) {
      const int c = i * 256 + tid;
      const int lane = c & 63, s = (c >> 6) & 7, ktl = (c >> 9) & 1, hl = c >> 10;
      const int lq = lane & 31, hi2 = lane >> 5;
      const int rl = ktl * 64 + (s & 1) * 32 + lq;
      const int cc = hl * 128 + (s >> 1) * 32 + hi2 * 16;
      uint4v v = *(const uint4v*)((const char*)T + rl * 256 + (cc ^ ((rl & 7) << 4)));
      const int bh = b * 16 + ((bn & 1023) >> 6) + hl;
      const int kt2 = (nbase >> 6) + ktl;
      *(uint4v*)(Kb + ((((size_t)bh * 32 + kt2) * 8 + s) * 64 + lane) * 8) = v;
    }
  } else {
#pragma unroll
    for (int i = 0; i < 8; ++i) {
      const int c = i * 256 + tid;
      const int lane = c & 63, s = (c >> 6) & 7, ktl = (c >> 9) & 1, hl = c >> 10;
      const int lq = lane & 31, hi2 = lane >> 5;
      const int cl = hl * 64 + (s & 1) * 32 + lq;
      const int cc = ktl * 128 + (s >> 1) * 32 + hi2 * 16;
      uint4v v = *(const uint4v*)((const char*)T + cl * 256 + (cc ^ ((cl & 7) << 4)));
      const int bh = b * 16 + ((bn & 1023) >> 6) + hl;
      const int kt2 = (nbase >> 6) + ktl;
      *(uint4v*)(Vb + ((((size_t)bh * 32 + kt2) * 8 + s) * 64 + lane) * 8) = v;
    }
  }
}

// ------- proj GEMM v2: 128x64 tile, BK=64, 48 KiB LDS -> 3 blocks/CU -------
// Grid 32x16 = 512 blocks (was 256 = 1 block/CU). Same 2-phase schedule.
// 4 waves as 2(M) x 2(N): wave covers 64 rows x 32 cols; acc[4][2].
__global__ __launch_bounds__(256, 2) void gemm_proj(
    const u16* __restrict__ A, const u16* __restrict__ Bt, int M, int N, int K,
    const float* __restrict__ bias, float* __restrict__ outF) {
  const int bm = blockIdx.x * 128;
  const int bn = blockIdx.y * 64;
  const int tid = threadIdx.x;
  const int wid = tid >> 6;
  const int lr = tid & 15;
  const int lg = (tid >> 4) & 3;
  const int wr = wid >> 1, wc = wid & 1;

  __shared__ u16 smem[24576];  // 48 KiB
  u16* Ab0 = smem;             // [128][64] = 8192
  u16* Ab1 = smem + 8192;
  u16* Bb0 = smem + 16384;     // [64][64] = 4096
  u16* Bb1 = smem + 20480;

  f32x4 acc[4][2] = {};

  const int rowi = tid >> 3;
  const int sslot = ((tid & 7) ^ (rowi & 7)) * 8;
  const u16* Ag = A + (size_t)bm * K;
  const u16* Bg = Bt + (size_t)bn * K;
  const int nkt = K >> 6;

  auto stage = [&](u16* Ad, u16* Bd, int kt) {
    const int kof = kt << 6;
#pragma unroll
    for (int i = 0; i < 4; ++i) {
      const int row = i * 32 + rowi;
      gload_lds16(Ag + (size_t)row * K + kof + sslot, Ad + (i * 32 + wid * 8) * 64);
    }
#pragma unroll
    for (int i = 0; i < 2; ++i) {
      const int row = i * 32 + rowi;
      gload_lds16(Bg + (size_t)row * K + kof + sslot, Bd + (i * 32 + wid * 8) * 64);
    }
  };

  stage(Ab0, Bb0, 0);
  __syncthreads();

  for (int kt = 0; kt < nkt; ++kt) {
    const int p = kt & 1;
    const char* Ard = (const char*)(p ? Ab1 : Ab0);
    const char* Brd = (const char*)(p ? Bb1 : Bb0);
    bf16x8 af[4], bfr[2];
#pragma unroll
    for (int c = 0; c < 2; ++c) {
#pragma unroll
      for (int t = 0; t < 4; ++t) {
        const int ra = wr * 64 + t * 16 + lr;
        af[t] = *(const bf16x8*)(Ard + ra * 128 +
                                 ((c * 64 + lg * 16) ^ ((ra & 7) << 4)));
      }
#pragma unroll
      for (int t = 0; t < 2; ++t) {
        const int rb = wc * 32 + t * 16 + lr;
        bfr[t] = *(const bf16x8*)(Brd + rb * 128 +
                                  ((c * 64 + lg * 16) ^ ((rb & 7) << 4)));
      }
      if (c == 0 && kt + 1 < nkt) stage(p ? Ab0 : Ab1, p ? Bb0 : Bb1, kt + 1);
      __builtin_amdgcn_s_setprio(1);
#pragma unroll
      for (int mt = 0; mt < 4; ++mt)
#pragma unroll
        for (int nt = 0; nt < 2; ++nt)
          acc[mt][nt] = __builtin_amdgcn_mfma_f32_16x16x32_bf16(
              af[mt], bfr[nt], acc[mt][nt], 0, 0, 0);
      __builtin_amdgcn_s_setprio(0);
    }
    __syncthreads();
  }

#pragma unroll
  for (int mt = 0; mt < 4; ++mt) {
    const int row0 = bm + wr * 64 + mt * 16 + lg * 4;
#pragma unroll
    for (int nt = 0; nt < 2; ++nt) {
      const int col = bn + wc * 32 + nt * 16 + lr;
      const float bv = bias[col];
#pragma unroll
      for (int r = 0; r < 4; ++r)
        outF[(size_t)(row0 + r) * N + col] = acc[mt][nt][r] + bv;
    }
  }
}

// ------- flash attention v14: v13 minus setprio (lockstep -> T5 null/neg) ---
__global__ __launch_bounds__(512, 2) void flash_attn14(const u16* __restrict__ Qb,
                                                       const u16* __restrict__ Kp,
                                                       const u16* __restrict__ Vp,
                                                       u16* __restrict__ AO) {
  const int bh = blockIdx.x & 31;
  const int qt = blockIdx.x >> 5;   // 0..15
  const int tid = threadIdx.x;
  const int w = tid >> 6;
  const int qw = w & 3;
  const int half = w >> 2;
  const int lane = tid & 63;
  const int lq = lane & 31;
  const int hi = lane >> 5;
  const int q0 = qt * 128 + qw * 32;

  __shared__ u16 smem[32768];  // 64 KiB

  const u16* Qg = Qb + ((size_t)bh * 2048 + q0 + lq) * 64 + 8 * hi;
  bf16x8 qf[4];
#pragma unroll
  for (int t = 0; t < 4; ++t) qf[t] = *(const bf16x8*)(Qg + 16 * t);

  const u16* Kg = Kp + (size_t)bh * (32 * 4096);
  const u16* Vg = Vp + (size_t)bh * (32 * 4096);

  f32x16 ot0 = {}, ot1 = {};
  float lacc[8] = {};

  auto stage = [&](int buf, int ph) {
#pragma unroll
    for (int h = 0; h < 2; ++h) {
      const size_t src = (size_t)(h * 16 + ph) * 4096;
      gload_lds16(Kg + src + tid * 8, smem + (buf * 2 + h) * 4096 + tid * 8);
      gload_lds16(Vg + src + tid * 8, smem + 16384 + (buf * 2 + h) * 4096 + tid * 8);
    }
  };

  auto compute = [&](int buf) {
    const u16* Kl = smem + (buf * 2 + half) * 4096;
    const u16* Vl = smem + 16384 + (buf * 2 + half) * 4096;

    bf16x8 kf[8];
#pragma unroll
    for (int s = 0; s < 8; ++s)
      kf[s] = *(const bf16x8*)&Kl[s * 512 + lane * 8];

    f32x16 sa = {}, sb = {};
#pragma unroll
    for (int t = 0; t < 4; ++t) {
      sa = __builtin_amdgcn_mfma_f32_32x32x16_bf16(kf[2 * t], qf[t], sa, 0, 0, 0);
      sb = __builtin_amdgcn_mfma_f32_32x32x16_bf16(kf[2 * t + 1], qf[t], sb, 0, 0, 0);
    }

    bf16x8 vf[8];
#pragma unroll
    for (int s = 0; s < 8; ++s)
      vf[s] = *(const bf16x8*)&Vl[s * 512 + lane * 8];

#pragma unroll
    for (int r = 0; r < 16; ++r) {
      sa[r] = __builtin_amdgcn_exp2f(sa[r]);
      sb[r] = __builtin_amdgcn_exp2f(sb[r]);
    }
#pragma unroll
    for (int r = 0; r < 8; ++r)
      lacc[r] += (sa[r] + sa[r + 8]) + (sb[r] + sb[r + 8]);

    unsigned Ua[8], Ub[8];
#pragma unroll
    for (int s = 0; s < 4; ++s)
#pragma unroll
      for (int m2 = 0; m2 < 2; ++m2) {
        Ua[s * 2 + m2] = cvt_pk_bf16(sa[4 * s + 2 * m2], sa[4 * s + 2 * m2 + 1]);
        Ub[s * 2 + m2] = cvt_pk_bf16(sb[4 * s + 2 * m2], sb[4 * s + 2 * m2 + 1]);
      }
    bf16x8 pfrag[4];
#pragma unroll
    for (int t = 0; t < 4; ++t) {
      const unsigned* U = (t < 2) ? Ua : Ub;
      const int tt = t & 1;
      unsigned w0 = U[(2 * tt) * 2 + 0], w2 = U[(2 * tt + 1) * 2 + 0];
      unsigned w1 = U[(2 * tt) * 2 + 1], w3 = U[(2 * tt + 1) * 2 + 1];
      perm32swap(w0, w2);
      perm32swap(w1, w3);
      uint4v uu = {w0, w1, w2, w3};
      pfrag[t] = __builtin_bit_cast(bf16x8, uu);
    }

#pragma unroll
    for (int t = 0; t < 4; ++t) {
      ot0 = __builtin_amdgcn_mfma_f32_32x32x16_bf16(vf[2 * t], pfrag[t], ot0, 0, 0, 0);
      ot1 = __builtin_amdgcn_mfma_f32_32x32x16_bf16(vf[2 * t + 1], pfrag[t], ot1, 0, 0, 0);
    }
  };

  stage(0, 0);
  __syncthreads();

  for (int ph = 0; ph < 16; ++ph) {
    const int p = ph & 1;
    if (ph < 15) stage(p ^ 1, ph + 1);
    compute(p);
    __syncthreads();
  }

  float lsum = ((lacc[0] + lacc[1]) + (lacc[2] + lacc[3])) +
               ((lacc[4] + lacc[5]) + (lacc[6] + lacc[7]));
  lsum += __shfl_xor(lsum, 32, 64);

  float* mp = (float*)smem + ((size_t)qw * 64 + lane) * 33;
  if (half == 1) {
#pragma unroll
    for (int r = 0; r < 16; ++r) mp[r] = ot0[r];
#pragma unroll
    for (int r = 0; r < 16; ++r) mp[16 + r] = ot1[r];
    mp[32] = lsum;
  }
  __syncthreads();
  if (half == 1) return;

  const float inv = 1.0f / (lsum + mp[32]);
#pragma unroll
  for (int r = 0; r < 16; ++r) ot0[r] = (ot0[r] + mp[r]) * inv;
#pragma unroll
  for (int r = 0; r < 16; ++r) ot1[r] = (ot1[r] + mp[16 + r]) * inv;

  const int b = bh >> 4, h = bh & 15;
  u16* Ao = AO + ((size_t)(b * 2048 + q0 + lq)) * 1024 + h * 64;
#pragma unroll
  for (int s = 0; s < 4; ++s) {
    {
      const int d = 8 * s + 4 * hi;
      ushort4v pk;
#pragma unroll
      for (int i = 0; i < 4; ++i) pk[i] = f2bf(ot0[4 * s + i]);
      *(ushort4v*)(Ao + d) = pk;
    }
    {
      const int d = 32 + 8 * s + 4 * hi;
      ushort4v pk;
#pragma unroll
      for (int i = 0; i < 4; ++i) pk[i] = f2bf(ot1[4 * s + i]);
      *(ushort4v*)(Ao + d) = pk;
    }
  }
}

// ---------------- launch ----------------
extern "C" void kernel_launch(void* const* d_in, const int* in_sizes, int n_in,
                              void* d_out, int out_size, void* d_ws, size_t ws_size,
                              hipStream_t stream) {
  const float* x = (const float*)d_in[0];
  const float* w_qkv = (const float*)d_in[1];
  const float* b_qkv = (const float*)d_in[2];
  const float* w_proj = (const float*)d_in[3];
  const float* b_proj = (const float*)d_in[4];
  float* out = (float*)d_out;

  char* ws = (char*)d_ws;
  u16* xb = (u16*)(ws);                          // 8 MiB  [4096][1024]
  u16* wqT = (u16*)(ws + (8ull << 20));          // 6 MiB  [3072][1024]
  u16* wpT = (u16*)(ws + (14ull << 20));         // 2 MiB  [1024][1024]
  u16* Qb = (u16*)(ws + (16ull << 20));          // 8 MiB  [32][2048][64]
  u16* Kp = (u16*)(ws + (24ull << 20));          // 8 MiB  packed frags
  u16* Vp = (u16*)(ws + (32ull << 20));          // 8 MiB  packed frags
  u16* AO = (u16*)(ws + (40ull << 20));          // 8 MiB  [4096][1024]

  fused_pre<<<dim3(3072), dim3(256), 0, stream>>>(x, xb, w_qkv, wqT, w_proj, wpT);
  gemm_qkv<<<dim3(32, 24), dim3(256), 0, stream>>>(xb, wqT, b_qkv, Qb, Kp, Vp);
  flash_attn14<<<dim3(512), dim3(512), 0, stream>>>(Qb, Kp, Vp, AO);
  gemm_proj<<<dim3(32, 16), dim3(256), 0, stream>>>(AO, wpT, 4096, 1024, 1024,
                                                    b_proj, out);
}